// Round 4
// baseline (253.285 us; speedup 1.0000x reference)
//
#include <hip/hip_runtime.h>
#include <hip/hip_bf16.h>
#include <math.h>

// Problem constants
constexpr int NN = 50000;   // nodes
constexpr int NE = 800000;  // edges (without self loops)
constexpr int ET = NE + NN; // edges + self loops
constexpr int FH = 128;     // HEADS*HID = feature width (also IN_CH)
constexpr int NHEAD = 4;
constexpr int NG = 64;      // graphs
constexpr int OC = 10;      // out channels

// Multisplit CSR build: buckets of 256 nodes (bucket = dst >> 8).
// Zero global atomics anywhere (global atomics write through to the memory
// side, ~32B each -- round-1 counters).
constexpr int NBK = (NN + 255) >> 8;   // 196 buckets
constexpr int EPB = 4000;              // edges per hist/scatter block
constexpr int HBLK = NE / EPB;         // 200 blocks

// W^T pack: [128 n][136 k] ushort, padded to 136 for LDS bank stagger
constexpr int WKP = 136;
constexpr int WPLANE = 128 * WKP;   // ushorts per plane (hi or lo)

constexpr int GEMM1_GRID = (NN + 255) / 256;  // 196 blocks x 1024 thr (16 waves)
constexpr int GEMM2_GRID = (NN + 63) / 64;    // 782 blocks x 256 thr

typedef __attribute__((ext_vector_type(8))) short short8;
typedef __attribute__((ext_vector_type(4))) float f32x4;

__device__ inline ushort f2bf_bits(float f) {
    union { __hip_bfloat16 h; ushort u; } c;
    c.h = __float2bfloat16(f);
    return c.u;
}

// ---------------------------------------------------------------------------
// MFMA GEMM + attention epilogue (per-wave; wave/row0 set by caller).
// C/D layout: col=lane&15, row=quad*4+reg.
// ---------------------------------------------------------------------------
#define GEMM_EPILOGUE()                                                          \
    float as_[8], ad_[8];                                                        \
    _Pragma("unroll")                                                            \
    for (int t = 0; t < 8; ++t) {                                                \
        as_[t] = att_s[t * 16 + l16];                                            \
        ad_[t] = att_d[t * 16 + l16];                                            \
    }                                                                            \
    float hs[4][4], hd[4][4];                                                    \
    _Pragma("unroll")                                                            \
    for (int r = 0; r < 4; ++r) {                                                \
        int grow = row0 + quad * 4 + r;                                          \
        bool okr = (grow < NN);                                                  \
        _Pragma("unroll")                                                        \
        for (int h = 0; h < 4; ++h) {                                            \
            hs[r][h] = acc[2*h][r] * as_[2*h] + acc[2*h+1][r] * as_[2*h+1];      \
            hd[r][h] = acc[2*h][r] * ad_[2*h] + acc[2*h+1][r] * ad_[2*h+1];      \
        }                                                                        \
        if (okr) {                                                               \
            _Pragma("unroll")                                                    \
            for (int t = 0; t < 8; ++t)                                          \
                Hb[(size_t)grow * FH + t * 16 + l16] = __float2bfloat16(acc[t][r]); \
        }                                                                        \
    }                                                                            \
    _Pragma("unroll")                                                            \
    for (int o = 1; o < 16; o <<= 1) {                                           \
        _Pragma("unroll")                                                        \
        for (int r = 0; r < 4; ++r)                                              \
            _Pragma("unroll")                                                    \
            for (int h = 0; h < 4; ++h) {                                        \
                hs[r][h] += __shfl_xor(hs[r][h], o);                             \
                hd[r][h] += __shfl_xor(hd[r][h], o);                             \
            }                                                                    \
    }                                                                            \
    if (l16 == 0) {                                                              \
        _Pragma("unroll")                                                        \
        for (int r = 0; r < 4; ++r) {                                            \
            int grow = row0 + quad * 4 + r;                                      \
            if (grow < NN) {                                                     \
                *(float4*)&a_src[grow * NHEAD] = make_float4(hs[r][0], hs[r][1], hs[r][2], hs[r][3]); \
                *(float4*)&a_dst[grow * NHEAD] = make_float4(hd[r][0], hd[r][1], hd[r][2], hd[r][3]); \
            }                                                                    \
        }                                                                        \
    }

// ---------------------------------------------------------------------------
// Fused dispatch (1024 threads):
//  blocks [0, GEMM1_GRID): layer-1 GEMM; converts W1 f32 -> split-bf16 LDS
//    in-kernel (no separate pack dispatch needed for layer 1).
//  blocks [GEMM1_GRID, +HBLK): per-block bucket histogram (LDS atomics only,
//    plain stores) + side job: first 64 of them pack W2 into wt (read only
//    by the later gemm2 dispatch).
// ---------------------------------------------------------------------------
__global__ __launch_bounds__(1024) void fused_gemm_hist_kernel(
    const int* __restrict__ ei, int* __restrict__ blockHist,
    const float* __restrict__ A, const float* __restrict__ W1,
    const float* __restrict__ W2, ushort* __restrict__ wt,
    const float* __restrict__ att_s, const float* __restrict__ att_d,
    __hip_bfloat16* __restrict__ Hb, float* __restrict__ a_src, float* __restrict__ a_dst)
{
    __shared__ ushort Wlds[2 * WPLANE];
    const int tid = threadIdx.x;

    if (blockIdx.x >= GEMM1_GRID) {
        const int blk = blockIdx.x - GEMM1_GRID;
        int* hist = (int*)Wlds;
        if (tid < NBK) hist[tid] = 0;
        __syncthreads();
        const int e0 = blk * EPB;
        if (tid < EPB / 4) {
            int4 d4 = *(const int4*)(ei + NE + e0 + 4 * tid);
            atomicAdd(&hist[d4.x >> 8], 1);
            atomicAdd(&hist[d4.y >> 8], 1);
            atomicAdd(&hist[d4.z >> 8], 1);
            atomicAdd(&hist[d4.w >> 8], 1);
        }
        // side job: pack W2 (split precision) for the later gemm2 dispatch
        if (blk < 64 && tid < 256) {
            int idx = blk * 256 + tid;          // 0..16383
            int k = idx >> 7, n = idx & 127;
            float f = W2[idx];
            ushort hb = f2bf_bits(f);
            union { ushort u; __hip_bfloat16 h; } c; c.u = hb;
            float lo = f - __bfloat162float(c.h);
            wt[n * WKP + k] = hb;
            wt[WPLANE + n * WKP + k] = f2bf_bits(lo);
        }
        __syncthreads();
        if (tid < NBK) blockHist[tid * HBLK + blk] = hist[tid];
        return;
    }

    // ---- layer-1 GEMM (f32 input, split precision), 16 waves ----
    // W1 f32 -> split-bf16 LDS conversion in-kernel
    for (int i = tid; i < FH * 128; i += 1024) {
        int k = i >> 7, n = i & 127;
        float f = W1[i];                        // W1[k*128+n]
        ushort hb = f2bf_bits(f);
        union { ushort u; __hip_bfloat16 h; } c; c.u = hb;
        float lo = f - __bfloat162float(c.h);
        Wlds[n * WKP + k] = hb;
        Wlds[WPLANE + n * WKP + k] = f2bf_bits(lo);
    }
    __syncthreads();

    const int wave = tid >> 6;         // 0..15
    const int lane = tid & 63;
    const int quad = lane >> 4;
    const int l16 = lane & 15;
    const int row0 = blockIdx.x * 256 + wave * 16;

    f32x4 acc[8];
#pragma unroll
    for (int t = 0; t < 8; ++t) acc[t] = (f32x4){0.f, 0.f, 0.f, 0.f};

    int arow = row0 + l16; if (arow >= NN) arow = NN - 1;
    const float* ap = A + (size_t)arow * FH + quad * 8;

#pragma unroll
    for (int kc = 0; kc < 4; ++kc) {
        float4 x0 = *(const float4*)(ap + kc * 32);
        float4 x1 = *(const float4*)(ap + kc * 32 + 4);
        float av[8] = {x0.x, x0.y, x0.z, x0.w, x1.x, x1.y, x1.z, x1.w};
        short8 ah, al;
#pragma unroll
        for (int j = 0; j < 8; ++j) {
            ushort hb = f2bf_bits(av[j]);
            union { ushort u; __hip_bfloat16 h; } c; c.u = hb;
            float lo = av[j] - __bfloat162float(c.h);
            ah[j] = (short)hb;
            al[j] = (short)f2bf_bits(lo);
        }
        const int kof = kc * 32 + quad * 8;
#pragma unroll
        for (int t = 0; t < 8; ++t) {
            const ushort* wp = &Wlds[(t * 16 + l16) * WKP + kof];
            short8 wh = *(const short8*)wp;
            short8 wl = *(const short8*)(wp + WPLANE);
            acc[t] = __builtin_amdgcn_mfma_f32_16x16x32_bf16(ah, wh, acc[t], 0, 0, 0);
            acc[t] = __builtin_amdgcn_mfma_f32_16x16x32_bf16(al, wh, acc[t], 0, 0, 0);
            acc[t] = __builtin_amdgcn_mfma_f32_16x16x32_bf16(ah, wl, acc[t], 0, 0, 0);
        }
    }
    GEMM_EPILOGUE()
}

// ---------------------------------------------------------------------------
// Merged scan: each of NBK blocks redundantly computes all bucket totals
// (39K L2-hit loads), scans them for its own global base, then scans its own
// bucket's HBLK counts and writes ABSOLUTE cursor starts to bstart.
// Separate output array (bstart) avoids read/write races on bh.
// Block 0 additionally publishes ebase[] and offs[NN].
// ---------------------------------------------------------------------------
__global__ __launch_bounds__(256) void scanAB_kernel(const int* __restrict__ bh,
                                                     int* __restrict__ bstart,
                                                     int* __restrict__ ebase,
                                                     int* __restrict__ offs) {
    __shared__ int sd[256];
    __shared__ int bprefix;
    const int b = blockIdx.x, t = threadIdx.x;
    int v = 0;
    if (t < NBK) {
        const int* p = bh + t * HBLK;
        for (int i = 0; i < HBLK; ++i) v += p[i];
    }
    sd[t] = v; __syncthreads();
#pragma unroll
    for (int o = 1; o < 256; o <<= 1) {
        int u = (t >= o) ? sd[t - o] : 0;
        __syncthreads();
        sd[t] += u;
        __syncthreads();
    }
    if (t == b) bprefix = sd[t] - v;   // exclusive prefix for this bucket
    if (b == 0) {
        if (t < NBK) ebase[t] = sd[t] - v;
        if (t == NBK - 1) ebase[NBK] = sd[t];   // == NE
        if (t == 0) offs[NN] = ET;
    }
    __syncthreads();
    const int base = bprefix;
    __syncthreads();
    // own-bucket scan over HBLK block counts
    int c = (t < HBLK) ? bh[b * HBLK + t] : 0;
    sd[t] = c; __syncthreads();
#pragma unroll
    for (int o = 1; o < 256; o <<= 1) {
        int u = (t >= o) ? sd[t - o] : 0;
        __syncthreads();
        sd[t] += u;
        __syncthreads();
    }
    if (t < HBLK) bstart[b * HBLK + t] = base + sd[t] - c;
}

// ---------------------------------------------------------------------------
// Bucket scatter: each block re-reads its EPB edges (src+dst, coalesced int4),
// places (src,dst) into its bucket region via LDS cursors (absolute starts
// from bstart). Plain 8B stores; slots globally unique by construction.
// ---------------------------------------------------------------------------
__global__ __launch_bounds__(1024) void bucket_scatter_kernel(
    const int* __restrict__ ei, const int* __restrict__ bstart,
    int2* __restrict__ ebuf) {
    __shared__ int cur[NBK];
    const int tid = threadIdx.x;
    const int blk = blockIdx.x;
    for (int i = tid; i < NBK; i += 1024) cur[i] = bstart[i * HBLK + blk];
    __syncthreads();
    const int e0 = blk * EPB;
    if (tid < EPB / 4) {
        int4 d4 = *(const int4*)(ei + NE + e0 + 4 * tid);
        int4 s4 = *(const int4*)(ei + e0 + 4 * tid);
        int ds[4] = {d4.x, d4.y, d4.z, d4.w};
        int ss[4] = {s4.x, s4.y, s4.z, s4.w};
#pragma unroll
        for (int j = 0; j < 4; ++j) {
            int pos = atomicAdd(&cur[ds[j] >> 8], 1);
            ebuf[pos] = make_int2(ss[j], ds[j]);
        }
    }
}

// ---------------------------------------------------------------------------
// Per-bucket CSR finalize: one block per bucket (256 nodes, ~4K edges).
// count (LDS) -> scan (LDS) -> write offs + self loops -> place csrc.
// offs[n] = ebase[b] + exdeg_within_bucket + n  (self loops included)
// ---------------------------------------------------------------------------
__global__ __launch_bounds__(256) void bucket_csr_kernel(
    const int2* __restrict__ ebuf, const int* __restrict__ ebase,
    int* __restrict__ offs, int* __restrict__ csrc) {
    __shared__ int hist[256];
    __shared__ int sd[256];
    __shared__ int cur[256];
    const int b = blockIdx.x, t = threadIdx.x;
    const int lo = b << 8;
    int psz = NN - lo; if (psz > 256) psz = 256;
    const int e0 = ebase[b], e1 = ebase[b + 1];

    hist[t] = 0;
    __syncthreads();
    for (int k = e0 + t; k < e1; k += 256) {
        int2 e = ebuf[k];
        atomicAdd(&hist[e.y - lo], 1);
    }
    __syncthreads();
    const int d = hist[t];
    sd[t] = d; __syncthreads();
#pragma unroll
    for (int o = 1; o < 256; o <<= 1) {
        int u = (t >= o) ? sd[t - o] : 0;
        __syncthreads();
        sd[t] += u;
        __syncthreads();
    }
    const int ex = sd[t] - d;
    if (t < psz) {
        const int node = lo + t;
        const int o = e0 + ex + node;
        offs[node] = o;
        cur[t] = o;
        csrc[o + d] = node;             // self loop at end of the node's range
    }
    __syncthreads();
    for (int k = e0 + t; k < e1; k += 256) {
        int2 e = ebuf[k];
        int pos = atomicAdd(&cur[e.y - lo], 1);
        csrc[pos] = e.x;
    }
}

__global__ __launch_bounds__(256) void gemm_att_bf16_kernel(
    const __hip_bfloat16* __restrict__ A, const ushort* __restrict__ wt,
    const float* __restrict__ att_s, const float* __restrict__ att_d,
    __hip_bfloat16* __restrict__ Hb, float* __restrict__ a_src, float* __restrict__ a_dst)
{
    __shared__ ushort Wlds[2 * WPLANE];
    const int tid = threadIdx.x;
    {
        const uint4* s = (const uint4*)wt;
        uint4* d = (uint4*)Wlds;
        for (int i = tid; i < 2 * WPLANE / 8; i += 256) d[i] = s[i];
    }
    __syncthreads();

    const int wave = tid >> 6;
    const int lane = tid & 63;
    const int quad = lane >> 4;
    const int l16 = lane & 15;
    const int row0 = blockIdx.x * 64 + wave * 16;

    f32x4 acc[8];
#pragma unroll
    for (int t = 0; t < 8; ++t) acc[t] = (f32x4){0.f, 0.f, 0.f, 0.f};

    int arow = row0 + l16; if (arow >= NN) arow = NN - 1;
    const __hip_bfloat16* ap = A + (size_t)arow * FH + quad * 8;

#pragma unroll
    for (int kc = 0; kc < 4; ++kc) {
        short8 ah = *(const short8*)(ap + kc * 32);
        const int kof = kc * 32 + quad * 8;
#pragma unroll
        for (int t = 0; t < 8; ++t) {
            const ushort* wp = &Wlds[(t * 16 + l16) * WKP + kof];
            short8 wh = *(const short8*)wp;
            short8 wl = *(const short8*)(wp + WPLANE);
            acc[t] = __builtin_amdgcn_mfma_f32_16x16x32_bf16(ah, wh, acc[t], 0, 0, 0);
            acc[t] = __builtin_amdgcn_mfma_f32_16x16x32_bf16(ah, wl, acc[t], 0, 0, 0);
        }
    }
    GEMM_EPILOGUE()
}

// ---------------------------------------------------------------------------
// Per-node aggregation, one wave per node, producer/consumer over 64-edge
// chunks. Producer: one LANE per edge (one csrc read, one float4 asrc
// gather, all 4 heads in-lane). LDS layout [edge][5] floats (w0..w3, src) --
// conflict-free for both producer writes and consumer reads.
// ---------------------------------------------------------------------------
__global__ __launch_bounds__(256) void gat_agg_kernel(
    const __hip_bfloat16* __restrict__ Hb, const float* __restrict__ asrc,
    const float* __restrict__ adst, const int* __restrict__ offs,
    const int* __restrict__ csrc, const float* __restrict__ bias,
    __hip_bfloat16* __restrict__ out)
{
    __shared__ float ebl[4][64][5];
    const int wid = threadIdx.x >> 6;
    const int lane = threadIdx.x & 63;
    const int n = blockIdx.x * 4 + wid;   // NN % 4 == 0, no bounds check

    const int beg = offs[n], end = offs[n + 1];
    const float4 ad4 = *(const float4*)&adst[n * NHEAD];
    const int es = lane >> 4;      // edge sub-slot 0..3
    const int fs = lane & 15;      // feature slot (8 feats each)
    const int hC = fs >> 2;        // head of these features
    const int f8 = fs * 8;
    float (*erow)[5] = ebl[wid];

    float dsum[4] = {0.f, 0.f, 0.f, 0.f};
    float acc[8];
#pragma unroll
    for (int i = 0; i < 8; ++i) acc[i] = 0.f;

    for (int cs = beg; cs < end; cs += 64) {
        int ce = end - cs; if (ce > 64) ce = 64;
        // producer: one lane per edge
        if (lane < ce) {
            int s = csrc[cs + lane];
            float4 av = *(const float4*)&asrc[s * NHEAD];
            float e0 = av.x + ad4.x; e0 = e0 > 0.f ? e0 : 0.2f * e0;
            float e1 = av.y + ad4.y; e1 = e1 > 0.f ? e1 : 0.2f * e1;
            float e2 = av.z + ad4.z; e2 = e2 > 0.f ? e2 : 0.2f * e2;
            float e3 = av.w + ad4.w; e3 = e3 > 0.f ? e3 : 0.2f * e3;
            float w0 = __expf(e0), w1 = __expf(e1), w2 = __expf(e2), w3 = __expf(e3);
            dsum[0] += w0; dsum[1] += w1; dsum[2] += w2; dsum[3] += w3;
            erow[lane][0] = w0; erow[lane][1] = w1;
            erow[lane][2] = w2; erow[lane][3] = w3;
            erow[lane][4] = __int_as_float(s);
        }
        __asm__ volatile("s_waitcnt lgkmcnt(0)" ::: "memory");
        // consumer: 8 edges / 2 independent chains per lane per iteration
        const int n8 = (ce + 7) >> 3;
        for (int p = 0; p < n8; ++p) {
            int eA = 8 * p + es;
            int eB = eA + 4;
            int iA = eA < ce ? eA : 0;
            int iB = eB < ce ? eB : 0;
            float wA = eA < ce ? erow[iA][hC] : 0.f;
            float wB = eB < ce ? erow[iB][hC] : 0.f;
            int sA = __float_as_int(erow[iA][4]);
            int sB = __float_as_int(erow[iB][4]);
            union { uint4 u; __hip_bfloat162 b[4]; } cvA, cvB;
            cvA.u = *(const uint4*)&Hb[(size_t)sA * FH + f8];
            cvB.u = *(const uint4*)&Hb[(size_t)sB * FH + f8];
#pragma unroll
            for (int i = 0; i < 4; ++i) {
                float2 hA = __bfloat1622float2(cvA.b[i]);
                float2 hB2 = __bfloat1622float2(cvB.b[i]);
                acc[2 * i]     = fmaf(wA, hA.x, acc[2 * i]);
                acc[2 * i + 1] = fmaf(wA, hA.y, acc[2 * i + 1]);
                acc[2 * i]     = fmaf(wB, hB2.x, acc[2 * i]);
                acc[2 * i + 1] = fmaf(wB, hB2.y, acc[2 * i + 1]);
            }
        }
    }
    // reduce per-head denominators over all 64 lanes
#pragma unroll
    for (int o = 1; o < 64; o <<= 1) {
#pragma unroll
        for (int h = 0; h < 4; ++h) dsum[h] += __shfl_xor(dsum[h], o);
    }
#pragma unroll
    for (int i = 0; i < 8; ++i) {
        acc[i] += __shfl_xor(acc[i], 16);
        acc[i] += __shfl_xor(acc[i], 32);
    }
    const float inv = 1.0f / dsum[hC];
    if (es == 0) {
        union { ushort u8[8]; uint4 u; } pk;
#pragma unroll
        for (int i = 0; i < 8; ++i) {
            float v = fmaxf(fmaf(acc[i], inv, bias[f8 + i]), 0.f);
            pk.u8[i] = f2bf_bits(v);
        }
        *(uint4*)&out[(size_t)n * FH + f8] = pk.u;
    }
}

// ---------------------------------------------------------------------------
// Mean pool + final linear fused: one block per graph (batch sorted ->
// boundaries via binary search), LDS tree-reduce, then 10 dot products.
// ---------------------------------------------------------------------------
__global__ __launch_bounds__(256) void pool_final_kernel(
    const __hip_bfloat16* __restrict__ X, const int* __restrict__ batch,
    const float* __restrict__ wl, const float* __restrict__ bl,
    float* __restrict__ out)
{
    const int g = blockIdx.x;
    const int t = threadIdx.x;
    int a = 0, b = NN;
    while (a < b) { int m = (a + b) >> 1; if (batch[m] < g) a = m + 1; else b = m; }
    const int gs = a;
    b = NN;
    while (a < b) { int m = (a + b) >> 1; if (batch[m] <= g) a = m + 1; else b = m; }
    const int ge = a;

    const int rg = t >> 4;       // row group 0..15
    const int l16 = t & 15;      // 16B feature slot
    float acc[8];
#pragma unroll
    for (int i = 0; i < 8; ++i) acc[i] = 0.f;
    for (int r = gs + rg; r < ge; r += 16) {
        union { uint4 u; __hip_bfloat162 bb[4]; } cv;
        cv.u = *(const uint4*)&X[(size_t)r * FH + l16 * 8];
#pragma unroll
        for (int i = 0; i < 4; ++i) {
            float2 f = __bfloat1622float2(cv.bb[i]);
            acc[2 * i]     += f.x;
            acc[2 * i + 1] += f.y;
        }
    }
    __shared__ float red[16][128];
    __shared__ float pl[128];
#pragma unroll
    for (int i = 0; i < 8; ++i) red[rg][l16 * 8 + i] = acc[i];
    __syncthreads();
    if (t < 128) {
        float s = 0.f;
#pragma unroll
        for (int j = 0; j < 16; ++j) s += red[j][t];
        pl[t] = s;
    }
    __syncthreads();
    if (t < OC) {
        float invc = 1.0f / fmaxf((float)(ge - gs), 1.0f);
        float a2 = 0.f;
        for (int k = 0; k < FH; ++k)
            a2 = fmaf(pl[k], wl[k * OC + t], a2);
        out[g * OC + t] = a2 * invc + bl[t];
    }
}

// ---------------------------------------------------------------------------
extern "C" void kernel_launch(void* const* d_in, const int* in_sizes, int n_in,
                              void* d_out, int out_size, void* d_ws, size_t ws_size,
                              hipStream_t stream) {
    const float* x       = (const float*)d_in[0];
    const int*   ei      = (const int*)d_in[1];   // [2, NE]
    const int*   batch   = (const int*)d_in[2];
    const float* W1      = (const float*)d_in[3];
    const float* as1     = (const float*)d_in[4];
    const float* ad1     = (const float*)d_in[5];
    const float* b1      = (const float*)d_in[6];
    const float* W2      = (const float*)d_in[7];
    const float* as2     = (const float*)d_in[8];
    const float* ad2     = (const float*)d_in[9];
    const float* b2      = (const float*)d_in[10];
    const float* wlin    = (const float*)d_in[11];
    const float* blin    = (const float*)d_in[12];
    float* out = (float*)d_out;

    // workspace layout (everything fully rewritten each call -> no memset)
    __hip_bfloat16* hbuf = (__hip_bfloat16*)d_ws;        // NN*FH bf16 (gemm out)
    __hip_bfloat16* abuf = hbuf + (size_t)NN * FH;       // NN*FH bf16 (agg out)
    float* asrc  = (float*)(abuf + (size_t)NN * FH);     // NN*4
    float* adst  = asrc + (size_t)NN * NHEAD;            // NN*4
    int* offs    = (int*)(adst + (size_t)NN * NHEAD);    // NN+1
    int* csrc    = offs + NN + 1;                        // ET
    int2* ebuf   = (int2*)(((uintptr_t)(csrc + ET) + 7) & ~(uintptr_t)7); // NE int2
    int* bh      = (int*)(ebuf + NE);         // NBK*HBLK
    int* bstart  = bh + NBK * HBLK;           // NBK*HBLK
    int* ebase   = bstart + NBK * HBLK;       // NBK+1
    ushort* wt   = (ushort*)(((uintptr_t)(ebase + NBK + 1) + 15) & ~(uintptr_t)15); // 2*WPLANE

    // 1. Fused: layer-1 GEMM (in-kernel W1 pack) + bucket hist + W2 pack
    fused_gemm_hist_kernel<<<GEMM1_GRID + HBLK, 1024, 0, stream>>>(
        ei, bh, x, W1, W2, wt, as1, ad1, hbuf, asrc, adst);

    // 2-4. CSR build
    scanAB_kernel<<<NBK, 256, 0, stream>>>(bh, bstart, ebase, offs);
    bucket_scatter_kernel<<<HBLK, 1024, 0, stream>>>(ei, bstart, ebuf);
    bucket_csr_kernel<<<NBK, 256, 0, stream>>>(ebuf, ebase, offs, csrc);

    const int agg_grid = NN / 4;

    // 5. Layer 1 aggregation
    gat_agg_kernel<<<agg_grid, 256, 0, stream>>>(hbuf, asrc, adst, offs, csrc, b1, abuf);
    // 6. Layer 2 GEMM
    gemm_att_bf16_kernel<<<GEMM2_GRID, 256, 0, stream>>>(abuf, wt, as2, ad2, hbuf, asrc, adst);
    // 7. Layer 2 aggregation
    gat_agg_kernel<<<agg_grid, 256, 0, stream>>>(hbuf, asrc, adst, offs, csrc, b2, abuf);

    // 8. Pool + final linear (fused)
    pool_final_kernel<<<NG, 256, 0, stream>>>(abuf, batch, wlin, blin, out);
}

// Round 5
// 253.229 us; speedup vs baseline: 1.0002x; 1.0002x over previous
//
#include <hip/hip_runtime.h>
#include <hip/hip_bf16.h>
#include <math.h>

// Problem constants
constexpr int NN = 50000;   // nodes
constexpr int NE = 800000;  // edges (without self loops)
constexpr int ET = NE + NN; // edges + self loops
constexpr int FH = 128;     // HEADS*HID = feature width (also IN_CH)
constexpr int NHEAD = 4;
constexpr int NG = 64;      // graphs
constexpr int OC = 10;      // out channels

// Multisplit CSR build: buckets of 256 nodes (bucket = dst >> 8).
// Zero global atomics anywhere (global atomics write through to the memory
// side, ~32B each -- round-1 counters).
constexpr int NBK = (NN + 255) >> 8;   // 196 buckets
constexpr int EPB = 4000;              // edges per hist/scatter block
constexpr int HBLK = NE / EPB;         // 200 blocks

// W^T pack: [128 n][136 k] ushort, padded to 136 for LDS bank stagger
constexpr int WKP = 136;
constexpr int WPLANE = 128 * WKP;   // ushorts per plane (hi or lo)

constexpr int GEMM1_GRID = (NN + 255) / 256;  // 196 blocks x 1024 thr (16 waves)
constexpr int GEMM2_GRID = (NN + 63) / 64;    // 782 blocks x 256 thr

typedef __attribute__((ext_vector_type(8))) short short8;
typedef __attribute__((ext_vector_type(4))) float f32x4;

__device__ inline ushort f2bf_bits(float f) {
    union { __hip_bfloat16 h; ushort u; } c;
    c.h = __float2bfloat16(f);
    return c.u;
}

// ---------------------------------------------------------------------------
// MFMA GEMM + attention epilogue (per-wave; wave/row0 set by caller).
// C/D layout: col=lane&15, row=quad*4+reg.
// ---------------------------------------------------------------------------
#define GEMM_EPILOGUE()                                                          \
    float as_[8], ad_[8];                                                        \
    _Pragma("unroll")                                                            \
    for (int t = 0; t < 8; ++t) {                                                \
        as_[t] = att_s[t * 16 + l16];                                            \
        ad_[t] = att_d[t * 16 + l16];                                            \
    }                                                                            \
    float hs[4][4], hd[4][4];                                                    \
    _Pragma("unroll")                                                            \
    for (int r = 0; r < 4; ++r) {                                                \
        int grow = row0 + quad * 4 + r;                                          \
        bool okr = (grow < NN);                                                  \
        _Pragma("unroll")                                                        \
        for (int h = 0; h < 4; ++h) {                                            \
            hs[r][h] = acc[2*h][r] * as_[2*h] + acc[2*h+1][r] * as_[2*h+1];      \
            hd[r][h] = acc[2*h][r] * ad_[2*h] + acc[2*h+1][r] * ad_[2*h+1];      \
        }                                                                        \
        if (okr) {                                                               \
            _Pragma("unroll")                                                    \
            for (int t = 0; t < 8; ++t)                                          \
                Hb[(size_t)grow * FH + t * 16 + l16] = __float2bfloat16(acc[t][r]); \
        }                                                                        \
    }                                                                            \
    _Pragma("unroll")                                                            \
    for (int o = 1; o < 16; o <<= 1) {                                           \
        _Pragma("unroll")                                                        \
        for (int r = 0; r < 4; ++r)                                              \
            _Pragma("unroll")                                                    \
            for (int h = 0; h < 4; ++h) {                                        \
                hs[r][h] += __shfl_xor(hs[r][h], o);                             \
                hd[r][h] += __shfl_xor(hd[r][h], o);                             \
            }                                                                    \
    }                                                                            \
    if (l16 == 0) {                                                              \
        _Pragma("unroll")                                                        \
        for (int r = 0; r < 4; ++r) {                                            \
            int grow = row0 + quad * 4 + r;                                      \
            if (grow < NN) {                                                     \
                *(float4*)&a_src[grow * NHEAD] = make_float4(hs[r][0], hs[r][1], hs[r][2], hs[r][3]); \
                *(float4*)&a_dst[grow * NHEAD] = make_float4(hd[r][0], hd[r][1], hd[r][2], hd[r][3]); \
            }                                                                    \
        }                                                                        \
    }

// ---------------------------------------------------------------------------
// Fused dispatch (1024 threads):
//  blocks [0, GEMM1_GRID): layer-1 GEMM; converts W1 f32 -> split-bf16 LDS
//    in-kernel (no separate pack dispatch needed for layer 1).
//  blocks [GEMM1_GRID, +HBLK): per-block bucket histogram (LDS atomics only,
//    plain stores) + side job: first 64 of them pack W2 into wt (read only
//    by the later gemm2 dispatch).
// ---------------------------------------------------------------------------
__global__ __launch_bounds__(1024) void fused_gemm_hist_kernel(
    const int* __restrict__ ei, int* __restrict__ blockHist,
    const float* __restrict__ A, const float* __restrict__ W1,
    const float* __restrict__ W2, ushort* __restrict__ wt,
    const float* __restrict__ att_s, const float* __restrict__ att_d,
    __hip_bfloat16* __restrict__ Hb, float* __restrict__ a_src, float* __restrict__ a_dst)
{
    __shared__ ushort Wlds[2 * WPLANE];
    const int tid = threadIdx.x;

    if (blockIdx.x >= GEMM1_GRID) {
        const int blk = blockIdx.x - GEMM1_GRID;
        int* hist = (int*)Wlds;
        if (tid < NBK) hist[tid] = 0;
        __syncthreads();
        const int e0 = blk * EPB;
        if (tid < EPB / 4) {
            int4 d4 = *(const int4*)(ei + NE + e0 + 4 * tid);
            atomicAdd(&hist[d4.x >> 8], 1);
            atomicAdd(&hist[d4.y >> 8], 1);
            atomicAdd(&hist[d4.z >> 8], 1);
            atomicAdd(&hist[d4.w >> 8], 1);
        }
        // side job: pack W2 (split precision) for the later gemm2 dispatch
        if (blk < 64 && tid < 256) {
            int idx = blk * 256 + tid;          // 0..16383
            int k = idx >> 7, n = idx & 127;
            float f = W2[idx];
            ushort hb = f2bf_bits(f);
            union { ushort u; __hip_bfloat16 h; } c; c.u = hb;
            float lo = f - __bfloat162float(c.h);
            wt[n * WKP + k] = hb;
            wt[WPLANE + n * WKP + k] = f2bf_bits(lo);
        }
        __syncthreads();
        if (tid < NBK) blockHist[tid * HBLK + blk] = hist[tid];
        return;
    }

    // ---- layer-1 GEMM (f32 input, split precision), 16 waves ----
    // W1 f32 -> split-bf16 LDS conversion in-kernel
    for (int i = tid; i < FH * 128; i += 1024) {
        int k = i >> 7, n = i & 127;
        float f = W1[i];                        // W1[k*128+n]
        ushort hb = f2bf_bits(f);
        union { ushort u; __hip_bfloat16 h; } c; c.u = hb;
        float lo = f - __bfloat162float(c.h);
        Wlds[n * WKP + k] = hb;
        Wlds[WPLANE + n * WKP + k] = f2bf_bits(lo);
    }
    __syncthreads();

    const int wave = tid >> 6;         // 0..15
    const int lane = tid & 63;
    const int quad = lane >> 4;
    const int l16 = lane & 15;
    const int row0 = blockIdx.x * 256 + wave * 16;

    f32x4 acc[8];
#pragma unroll
    for (int t = 0; t < 8; ++t) acc[t] = (f32x4){0.f, 0.f, 0.f, 0.f};

    int arow = row0 + l16; if (arow >= NN) arow = NN - 1;
    const float* ap = A + (size_t)arow * FH + quad * 8;

#pragma unroll
    for (int kc = 0; kc < 4; ++kc) {
        float4 x0 = *(const float4*)(ap + kc * 32);
        float4 x1 = *(const float4*)(ap + kc * 32 + 4);
        float av[8] = {x0.x, x0.y, x0.z, x0.w, x1.x, x1.y, x1.z, x1.w};
        short8 ah, al;
#pragma unroll
        for (int j = 0; j < 8; ++j) {
            ushort hb = f2bf_bits(av[j]);
            union { ushort u; __hip_bfloat16 h; } c; c.u = hb;
            float lo = av[j] - __bfloat162float(c.h);
            ah[j] = (short)hb;
            al[j] = (short)f2bf_bits(lo);
        }
        const int kof = kc * 32 + quad * 8;
#pragma unroll
        for (int t = 0; t < 8; ++t) {
            const ushort* wp = &Wlds[(t * 16 + l16) * WKP + kof];
            short8 wh = *(const short8*)wp;
            short8 wl = *(const short8*)(wp + WPLANE);
            acc[t] = __builtin_amdgcn_mfma_f32_16x16x32_bf16(ah, wh, acc[t], 0, 0, 0);
            acc[t] = __builtin_amdgcn_mfma_f32_16x16x32_bf16(al, wh, acc[t], 0, 0, 0);
            acc[t] = __builtin_amdgcn_mfma_f32_16x16x32_bf16(ah, wl, acc[t], 0, 0, 0);
        }
    }
    GEMM_EPILOGUE()
}

// ---------------------------------------------------------------------------
// Merged scan: each of NBK blocks redundantly computes all bucket totals
// (39K L2-hit loads), scans them for its own global base, then scans its own
// bucket's HBLK counts and writes ABSOLUTE cursor starts to bstart.
// Block 0 additionally publishes ebase[] and offs[NN].
// ---------------------------------------------------------------------------
__global__ __launch_bounds__(256) void scanAB_kernel(const int* __restrict__ bh,
                                                     int* __restrict__ bstart,
                                                     int* __restrict__ ebase,
                                                     int* __restrict__ offs) {
    __shared__ int sd[256];
    __shared__ int bprefix;
    const int b = blockIdx.x, t = threadIdx.x;
    int v = 0;
    if (t < NBK) {
        const int* p = bh + t * HBLK;
        for (int i = 0; i < HBLK; ++i) v += p[i];
    }
    sd[t] = v; __syncthreads();
#pragma unroll
    for (int o = 1; o < 256; o <<= 1) {
        int u = (t >= o) ? sd[t - o] : 0;
        __syncthreads();
        sd[t] += u;
        __syncthreads();
    }
    if (t == b) bprefix = sd[t] - v;   // exclusive prefix for this bucket
    if (b == 0) {
        if (t < NBK) ebase[t] = sd[t] - v;
        if (t == NBK - 1) ebase[NBK] = sd[t];   // == NE
        if (t == 0) offs[NN] = ET;
    }
    __syncthreads();
    const int base = bprefix;
    __syncthreads();
    // own-bucket scan over HBLK block counts
    int c = (t < HBLK) ? bh[b * HBLK + t] : 0;
    sd[t] = c; __syncthreads();
#pragma unroll
    for (int o = 1; o < 256; o <<= 1) {
        int u = (t >= o) ? sd[t - o] : 0;
        __syncthreads();
        sd[t] += u;
        __syncthreads();
    }
    if (t < HBLK) bstart[b * HBLK + t] = base + sd[t] - c;
}

// ---------------------------------------------------------------------------
// Bucket scatter: each block re-reads its EPB edges (src+dst, coalesced int4),
// places (src,dst) into its bucket region via LDS cursors (absolute starts
// from bstart). Plain 8B stores; slots globally unique by construction.
// ---------------------------------------------------------------------------
__global__ __launch_bounds__(1024) void bucket_scatter_kernel(
    const int* __restrict__ ei, const int* __restrict__ bstart,
    int2* __restrict__ ebuf) {
    __shared__ int cur[NBK];
    const int tid = threadIdx.x;
    const int blk = blockIdx.x;
    for (int i = tid; i < NBK; i += 1024) cur[i] = bstart[i * HBLK + blk];
    __syncthreads();
    const int e0 = blk * EPB;
    if (tid < EPB / 4) {
        int4 d4 = *(const int4*)(ei + NE + e0 + 4 * tid);
        int4 s4 = *(const int4*)(ei + e0 + 4 * tid);
        int ds[4] = {d4.x, d4.y, d4.z, d4.w};
        int ss[4] = {s4.x, s4.y, s4.z, s4.w};
#pragma unroll
        for (int j = 0; j < 4; ++j) {
            int pos = atomicAdd(&cur[ds[j] >> 8], 1);
            ebuf[pos] = make_int2(ss[j], ds[j]);
        }
    }
}

// ---------------------------------------------------------------------------
// Per-bucket CSR finalize: one block per bucket (256 nodes, ~4K edges).
// count (LDS) -> scan (LDS) -> write offs + self loops -> place csrc.
// offs[n] = ebase[b] + exdeg_within_bucket + n  (self loops included)
// ---------------------------------------------------------------------------
__global__ __launch_bounds__(256) void bucket_csr_kernel(
    const int2* __restrict__ ebuf, const int* __restrict__ ebase,
    int* __restrict__ offs, int* __restrict__ csrc) {
    __shared__ int hist[256];
    __shared__ int sd[256];
    __shared__ int cur[256];
    const int b = blockIdx.x, t = threadIdx.x;
    const int lo = b << 8;
    int psz = NN - lo; if (psz > 256) psz = 256;
    const int e0 = ebase[b], e1 = ebase[b + 1];

    hist[t] = 0;
    __syncthreads();
    for (int k = e0 + t; k < e1; k += 256) {
        int2 e = ebuf[k];
        atomicAdd(&hist[e.y - lo], 1);
    }
    __syncthreads();
    const int d = hist[t];
    sd[t] = d; __syncthreads();
#pragma unroll
    for (int o = 1; o < 256; o <<= 1) {
        int u = (t >= o) ? sd[t - o] : 0;
        __syncthreads();
        sd[t] += u;
        __syncthreads();
    }
    const int ex = sd[t] - d;
    if (t < psz) {
        const int node = lo + t;
        const int o = e0 + ex + node;
        offs[node] = o;
        cur[t] = o;
        csrc[o + d] = node;             // self loop at end of the node's range
    }
    __syncthreads();
    for (int k = e0 + t; k < e1; k += 256) {
        int2 e = ebuf[k];
        int pos = atomicAdd(&cur[e.y - lo], 1);
        csrc[pos] = e.x;
    }
}

__global__ __launch_bounds__(256) void gemm_att_bf16_kernel(
    const __hip_bfloat16* __restrict__ A, const ushort* __restrict__ wt,
    const float* __restrict__ att_s, const float* __restrict__ att_d,
    __hip_bfloat16* __restrict__ Hb, float* __restrict__ a_src, float* __restrict__ a_dst)
{
    __shared__ ushort Wlds[2 * WPLANE];
    const int tid = threadIdx.x;
    {
        const uint4* s = (const uint4*)wt;
        uint4* d = (uint4*)Wlds;
        for (int i = tid; i < 2 * WPLANE / 8; i += 256) d[i] = s[i];
    }
    __syncthreads();

    const int wave = tid >> 6;
    const int lane = tid & 63;
    const int quad = lane >> 4;
    const int l16 = lane & 15;
    const int row0 = blockIdx.x * 64 + wave * 16;

    f32x4 acc[8];
#pragma unroll
    for (int t = 0; t < 8; ++t) acc[t] = (f32x4){0.f, 0.f, 0.f, 0.f};

    int arow = row0 + l16; if (arow >= NN) arow = NN - 1;
    const __hip_bfloat16* ap = A + (size_t)arow * FH + quad * 8;

#pragma unroll
    for (int kc = 0; kc < 4; ++kc) {
        short8 ah = *(const short8*)(ap + kc * 32);
        const int kof = kc * 32 + quad * 8;
#pragma unroll
        for (int t = 0; t < 8; ++t) {
            const ushort* wp = &Wlds[(t * 16 + l16) * WKP + kof];
            short8 wh = *(const short8*)wp;
            short8 wl = *(const short8*)(wp + WPLANE);
            acc[t] = __builtin_amdgcn_mfma_f32_16x16x32_bf16(ah, wh, acc[t], 0, 0, 0);
            acc[t] = __builtin_amdgcn_mfma_f32_16x16x32_bf16(ah, wl, acc[t], 0, 0, 0);
        }
    }
    GEMM_EPILOGUE()
}

// ---------------------------------------------------------------------------
// Per-node aggregation, one wave per node, CONSUMER-ONLY straight-line form:
// no LDS, no producer phase, no waitcnt serialization. Lane = (es 0..3,
// fs 0..15). Each lane handles edges e = beg + 8p + es (+4 for chain B):
//   csrc[e] is wave-broadcast (16 lanes same addr), asrc 4-lane-shared,
//   exp recomputed per lane (VALU is idle). All n8 iterations' gathers are
//   independent -> full ILP across the 3-deep chain csrc -> asrc/Hb.
// Denominator: per-lane partial sum reduced over lanes sharing hC via
// shfl_xor {1,2,16,32}; each (edge,head) counted 4x -> inv = 4/sum.
// ---------------------------------------------------------------------------
__global__ __launch_bounds__(256) void gat_agg_kernel(
    const __hip_bfloat16* __restrict__ Hb, const float* __restrict__ asrc,
    const float* __restrict__ adst, const int* __restrict__ offs,
    const int* __restrict__ csrc, const float* __restrict__ bias,
    __hip_bfloat16* __restrict__ out)
{
    const int wid = threadIdx.x >> 6;
    const int lane = threadIdx.x & 63;
    const int n = blockIdx.x * 4 + wid;   // NN % 4 == 0, no bounds check

    const int beg = offs[n], end = offs[n + 1];
    const int es = lane >> 4;      // edge sub-slot 0..3
    const int fs = lane & 15;      // feature slot (8 feats each)
    const int hC = fs >> 2;        // head of these features
    const int f8 = fs * 8;
    const float adC = adst[n * NHEAD + hC];

    float dsum = 0.f;
    float acc[8];
#pragma unroll
    for (int i = 0; i < 8; ++i) acc[i] = 0.f;

    const int last = end - 1;
    const int n8 = (end - beg + 7) >> 3;
    for (int p = 0; p < n8; ++p) {
        const int eA = beg + 8 * p + es;
        const int eB = eA + 4;
        const bool vA = eA < end, vB = eB < end;
        const int sA = csrc[vA ? eA : last];
        const int sB = csrc[vB ? eB : last];
        float aA = asrc[sA * NHEAD + hC] + adC;
        float aB = asrc[sB * NHEAD + hC] + adC;
        aA = aA > 0.f ? aA : 0.2f * aA;
        aB = aB > 0.f ? aB : 0.2f * aB;
        const float wA = vA ? __expf(aA) : 0.f;
        const float wB = vB ? __expf(aB) : 0.f;
        dsum += wA + wB;
        union { uint4 u; __hip_bfloat162 b[4]; } cvA, cvB;
        cvA.u = *(const uint4*)&Hb[(size_t)sA * FH + f8];
        cvB.u = *(const uint4*)&Hb[(size_t)sB * FH + f8];
#pragma unroll
        for (int i = 0; i < 4; ++i) {
            float2 hA = __bfloat1622float2(cvA.b[i]);
            float2 hB2 = __bfloat1622float2(cvB.b[i]);
            acc[2 * i]     = fmaf(wA, hA.x, acc[2 * i]);
            acc[2 * i + 1] = fmaf(wA, hA.y, acc[2 * i + 1]);
            acc[2 * i]     = fmaf(wB, hB2.x, acc[2 * i]);
            acc[2 * i + 1] = fmaf(wB, hB2.y, acc[2 * i + 1]);
        }
    }
    // denominator: sum over the 16 lanes sharing hC (bits 1,2,16,32 of lane)
    dsum += __shfl_xor(dsum, 1);
    dsum += __shfl_xor(dsum, 2);
    dsum += __shfl_xor(dsum, 16);
    dsum += __shfl_xor(dsum, 32);
    // features: sum over es (lane bits 16,32)
#pragma unroll
    for (int i = 0; i < 8; ++i) {
        acc[i] += __shfl_xor(acc[i], 16);
        acc[i] += __shfl_xor(acc[i], 32);
    }
    const float inv = 4.0f / dsum;   // each (edge,head) counted by 4 lanes
    if (es == 0) {
        union { ushort u8[8]; uint4 u; } pk;
#pragma unroll
        for (int i = 0; i < 8; ++i) {
            float v = fmaxf(fmaf(acc[i], inv, bias[f8 + i]), 0.f);
            pk.u8[i] = f2bf_bits(v);
        }
        *(uint4*)&out[(size_t)n * FH + f8] = pk.u;
    }
}

// ---------------------------------------------------------------------------
// Mean pool + final linear fused: one block per graph (batch sorted ->
// boundaries via binary search), LDS tree-reduce, then 10 dot products.
// ---------------------------------------------------------------------------
__global__ __launch_bounds__(256) void pool_final_kernel(
    const __hip_bfloat16* __restrict__ X, const int* __restrict__ batch,
    const float* __restrict__ wl, const float* __restrict__ bl,
    float* __restrict__ out)
{
    const int g = blockIdx.x;
    const int t = threadIdx.x;
    int a = 0, b = NN;
    while (a < b) { int m = (a + b) >> 1; if (batch[m] < g) a = m + 1; else b = m; }
    const int gs = a;
    b = NN;
    while (a < b) { int m = (a + b) >> 1; if (batch[m] <= g) a = m + 1; else b = m; }
    const int ge = a;

    const int rg = t >> 4;       // row group 0..15
    const int l16 = t & 15;      // 16B feature slot
    float acc[8];
#pragma unroll
    for (int i = 0; i < 8; ++i) acc[i] = 0.f;
    for (int r = gs + rg; r < ge; r += 16) {
        union { uint4 u; __hip_bfloat162 bb[4]; } cv;
        cv.u = *(const uint4*)&X[(size_t)r * FH + l16 * 8];
#pragma unroll
        for (int i = 0; i < 4; ++i) {
            float2 f = __bfloat1622float2(cv.bb[i]);
            acc[2 * i]     += f.x;
            acc[2 * i + 1] += f.y;
        }
    }
    __shared__ float red[16][128];
    __shared__ float pl[128];
#pragma unroll
    for (int i = 0; i < 8; ++i) red[rg][l16 * 8 + i] = acc[i];
    __syncthreads();
    if (t < 128) {
        float s = 0.f;
#pragma unroll
        for (int j = 0; j < 16; ++j) s += red[j][t];
        pl[t] = s;
    }
    __syncthreads();
    if (t < OC) {
        float invc = 1.0f / fmaxf((float)(ge - gs), 1.0f);
        float a2 = 0.f;
        for (int k = 0; k < FH; ++k)
            a2 = fmaf(pl[k], wl[k * OC + t], a2);
        out[g * OC + t] = a2 * invc + bl[t];
    }
}

// ---------------------------------------------------------------------------
extern "C" void kernel_launch(void* const* d_in, const int* in_sizes, int n_in,
                              void* d_out, int out_size, void* d_ws, size_t ws_size,
                              hipStream_t stream) {
    const float* x       = (const float*)d_in[0];
    const int*   ei      = (const int*)d_in[1];   // [2, NE]
    const int*   batch   = (const int*)d_in[2];
    const float* W1      = (const float*)d_in[3];
    const float* as1     = (const float*)d_in[4];
    const float* ad1     = (const float*)d_in[5];
    const float* b1      = (const float*)d_in[6];
    const float* W2      = (const float*)d_in[7];
    const float* as2     = (const float*)d_in[8];
    const float* ad2     = (const float*)d_in[9];
    const float* b2      = (const float*)d_in[10];
    const float* wlin    = (const float*)d_in[11];
    const float* blin    = (const float*)d_in[12];
    float* out = (float*)d_out;

    // workspace layout (everything fully rewritten each call -> no memset)
    __hip_bfloat16* hbuf = (__hip_bfloat16*)d_ws;        // NN*FH bf16 (gemm out)
    __hip_bfloat16* abuf = hbuf + (size_t)NN * FH;       // NN*FH bf16 (agg out)
    float* asrc  = (float*)(abuf + (size_t)NN * FH);     // NN*4
    float* adst  = asrc + (size_t)NN * NHEAD;            // NN*4
    int* offs    = (int*)(adst + (size_t)NN * NHEAD);    // NN+1
    int* csrc    = offs + NN + 1;                        // ET
    int2* ebuf   = (int2*)(((uintptr_t)(csrc + ET) + 7) & ~(uintptr_t)7); // NE int2
    int* bh      = (int*)(ebuf + NE);         // NBK*HBLK
    int* bstart  = bh + NBK * HBLK;           // NBK*HBLK
    int* ebase   = bstart + NBK * HBLK;       // NBK+1
    ushort* wt   = (ushort*)(((uintptr_t)(ebase + NBK + 1) + 15) & ~(uintptr_t)15); // 2*WPLANE

    // 1. Fused: layer-1 GEMM (in-kernel W1 pack) + bucket hist + W2 pack
    fused_gemm_hist_kernel<<<GEMM1_GRID + HBLK, 1024, 0, stream>>>(
        ei, bh, x, W1, W2, wt, as1, ad1, hbuf, asrc, adst);

    // 2-4. CSR build
    scanAB_kernel<<<NBK, 256, 0, stream>>>(bh, bstart, ebase, offs);
    bucket_scatter_kernel<<<HBLK, 1024, 0, stream>>>(ei, bstart, ebuf);
    bucket_csr_kernel<<<NBK, 256, 0, stream>>>(ebuf, ebase, offs, csrc);

    const int agg_grid = NN / 4;

    // 5. Layer 1 aggregation
    gat_agg_kernel<<<agg_grid, 256, 0, stream>>>(hbuf, asrc, adst, offs, csrc, b1, abuf);
    // 6. Layer 2 GEMM
    gemm_att_bf16_kernel<<<GEMM2_GRID, 256, 0, stream>>>(abuf, wt, as2, ad2, hbuf, asrc, adst);
    // 7. Layer 2 aggregation
    gat_agg_kernel<<<agg_grid, 256, 0, stream>>>(hbuf, asrc, adst, offs, csrc, b2, abuf);

    // 8. Pool + final linear (fused)
    pool_final_kernel<<<NG, 256, 0, stream>>>(abuf, batch, wlin, blin, out);
}